// Round 6
// baseline (8439.013 us; speedup 1.0000x reference)
//
#include <hip/hip_runtime.h>
#include <stdint.h>

// Problem dims (fixed)
#define B_  256
#define T_  1024
#define D_  128
#define H_  512
#define G4_ 2048            // 4*H
#define BT_ (B_ * T_)

// Persistent-LSTM partitioning: 16 batch groups x 16 col groups = 256 WGs
#define NG_ 16              // batch groups (16 rows each)
#define NC_ 16              // col groups (32 h-cols each)

typedef unsigned short u16;
typedef __attribute__((ext_vector_type(8))) short    bf16x8;  // 8 bf16 in 4 VGPRs
typedef __attribute__((ext_vector_type(8))) u16      u16x8;
typedef __attribute__((ext_vector_type(4))) float    f32x4;
typedef __attribute__((ext_vector_type(4))) uint32_t u32x4;

static __device__ __forceinline__ u16 f2bf(float f) {
  uint32_t u = __builtin_bit_cast(uint32_t, f);
  u += 0x7FFFu + ((u >> 16) & 1u);   // RNE
  return (u16)(u >> 16);
}

static __device__ __forceinline__ u16x8 pack8(float4 a, float4 b) {
  u16x8 p;
  p[0] = f2bf(a.x); p[1] = f2bf(a.y); p[2] = f2bf(a.z); p[3] = f2bf(a.w);
  p[4] = f2bf(b.x); p[5] = f2bf(b.y); p[6] = f2bf(b.z); p[7] = f2bf(b.w);
  return p;
}

static __device__ __forceinline__ float fast_sig(float x) {
  return 1.f / (1.f + __expf(-x));
}
static __device__ __forceinline__ float fast_tanh(float x) {
  return 1.f - 2.f / (__expf(2.f * x) + 1.f);
}

// ---------------------------------------------------------------------------
// prep: bf16 weight copies, bias sum, zero exchange buffer and out[:,0,:]
// ---------------------------------------------------------------------------
__global__ void prep_kernel(const float* __restrict__ Whh, const float* __restrict__ Wih,
                            const float* __restrict__ w1,  const float* __restrict__ w2,
                            const float* __restrict__ b_ih, const float* __restrict__ b_hh,
                            u16* __restrict__ Whh_bf, u16* __restrict__ Wih_bf,
                            u16* __restrict__ w1y_bf, u16* __restrict__ w2_bf,
                            float* __restrict__ w1s, float* __restrict__ bsum,
                            uint32_t* __restrict__ xch32, float* __restrict__ Yd) {
  const int idx = blockIdx.x * blockDim.x + threadIdx.x;
  if (idx < G4_ * H_) Whh_bf[idx] = f2bf(Whh[idx]);          // 1,048,576
  if (idx < G4_ * D_) Wih_bf[idx] = f2bf(Wih[idx]);          // 262,144
  if (idx < H_ * H_) {                                       // 262,144
    const int n = idx >> 9, k = idx & 511;
    w1y_bf[idx] = f2bf(w1[n * 513 + 1 + k]);                 // w1[:,1:]
    w2_bf[idx]  = f2bf(w2[idx]);
  }
  if (idx < H_)  w1s[idx]  = w1[idx * 513];                  // w1[:,0]
  if (idx < G4_) bsum[idx] = b_ih[idx] + b_hh[idx];
  if (idx < 2 * B_ * H_) xch32[idx] = 0;                     // 262,144 (tag 0)
  if (idx < B_ * H_) {                                       // 131,072
    const int b = idx >> 9, h = idx & 511;
    Yd[(size_t)b * T_ * H_ + h] = 0.f;                       // out[b,0,:] = h_0 = 0
  }
}

// ---------------------------------------------------------------------------
// Phase 1: persistent LSTM v4. Grid = 256 WGs x 256 thr (4 waves).
// WG (g,c): rows [g*16,+16), h-cols [c*32,+32). Wave gw = one gate (160 VGPR
// of weights per lane, pinned by an asm memory fence after the load loop).
//
// Exchange: SELF-VALIDATING tagged words. Producer packs (bf16(h)<<16)|step
// per u32, stores pairs as one relaxed agent-scope u64 (MALL write-through).
// Consumers poll their own 128 B (8x dwordx4 sc0 sc1, fully coalesced) until
// all 32 tags match the step — detection and payload arrive together (1 MALL
// RT instead of flag protocol's 3). Parity double-buffer: overwriting parity
// p at step s+1 is safe because polling success at step s proves every peer
// published s, hence finished reading p (same argument as R3). Tags 1..1023;
// prep zeroes the buffer each call (replay-safe).
// Barriers: only 2/step — (1) post-stage pre-MFMA, (2) post-gate-exchange.
// Loop-end hazards are covered transitively by poll success (see analysis).
// ---------------------------------------------------------------------------
__launch_bounds__(256, 1)
__global__ void lstm_persist3(const float* __restrict__ x,
                              const u16* __restrict__ Whh_bf,
                              const u16* __restrict__ Wih_bf,
                              const float* __restrict__ bsum,
                              float* __restrict__ Yd,
                              uint32_t* __restrict__ xch32) {
  __shared__ u16   As[16][648];       // 16 x 640 bf16 A-tile (+pad)
  __shared__ float Gs[4][16][34];     // gate exchange

  const int tid  = threadIdx.x;
  const int lane = tid & 63;
  const int gw   = tid >> 6;          // gate 0..3
  const int w    = blockIdx.x;
  const int g    = (w & 7) * 2 + (w >> 7);   // batch group (XCD-affine)
  const int c    = (w >> 3) & 15;            // col group
  const int br0  = g * 16;
  const int hc0  = c * 32;

  const int cl = lane & 15;
  const int ko = (lane >> 4) * 8;

  // ---- persistent weight fragments: gate gw, cols hc0..hc0+32 ----
  bf16x8 wf0[20], wf1[20];
  {
    const int j0 = gw * H_ + hc0 + cl;
#pragma unroll
    for (int kt = 0; kt < 16; ++kt) {
      wf0[kt] = *(const bf16x8*)(Whh_bf + (size_t)j0 * H_ + kt * 32 + ko);
      wf1[kt] = *(const bf16x8*)(Whh_bf + (size_t)(j0 + 16) * H_ + kt * 32 + ko);
    }
#pragma unroll
    for (int kt = 0; kt < 4; ++kt) {
      wf0[16 + kt] = *(const bf16x8*)(Wih_bf + (size_t)j0 * D_ + kt * 32 + ko);
      wf1[16 + kt] = *(const bf16x8*)(Wih_bf + (size_t)(j0 + 16) * D_ + kt * 32 + ko);
    }
  }
  // pin the fragments: loads cannot legally sink past this memory fence
  asm volatile("" ::: "memory");

  // ---- per-thread cell state: row er, cols (jb, jb+1) ----
  const int er = tid >> 4;            // 0..15
  const int ec = (tid & 15) * 2;      // 0..30
  const int jb = hc0 + ec;
  float c0 = 0.f, c1 = 0.f;
  const float bi0 = bsum[jb],            bi1 = bsum[jb + 1];
  const float bf0 = bsum[H_ + jb],       bf1 = bsum[H_ + jb + 1];
  const float bg0 = bsum[2 * H_ + jb],   bg1 = bsum[2 * H_ + jb + 1];
  const float bo0 = bsum[3 * H_ + jb],   bo1 = bsum[3 * H_ + jb + 1];

  const int xr   = tid & 15,  xk   = tid >> 4;   // x-stage map
  const int prow = tid >> 4;                     // poll row 0..15
  const int pcb  = (tid & 15) * 32;              // poll col base (u32 words)

  for (int s = 0; s < T_ - 1; ++s) {
    // ---- stage x-part (cols 512..639) — independent of h_s ----
    {
      const float4* x4 = (const float4*)(x + ((size_t)(br0 + xr) * T_ + s) * D_ + xk * 8);
      float4 a = x4[0], b = x4[1];
      *(u16x8*)&As[xr][512 + xk * 8] = pack8(a, b);
    }

    // ---- stage h-part (cols 0..511): coalesced tagged poll ----
    if (s == 0) {
      u16x8 z = {};
#pragma unroll
      for (int i = 0; i < 4; ++i) *(u16x8*)&As[prow][pcb + i * 8] = z;
    } else {
      const char* base = (const char*)(xch32 + (((size_t)(s & 1) * NG_ + g) << 13)) + tid * 128;
      const uint32_t want = (uint32_t)s;
      u32x4 r0, r1, r2, r3, r4, r5, r6, r7;
      bool ok;
      do {
        asm volatile(
          "global_load_dwordx4 %0, %8, off sc0 sc1\n\t"
          "global_load_dwordx4 %1, %8, off offset:16 sc0 sc1\n\t"
          "global_load_dwordx4 %2, %8, off offset:32 sc0 sc1\n\t"
          "global_load_dwordx4 %3, %8, off offset:48 sc0 sc1\n\t"
          "global_load_dwordx4 %4, %8, off offset:64 sc0 sc1\n\t"
          "global_load_dwordx4 %5, %8, off offset:80 sc0 sc1\n\t"
          "global_load_dwordx4 %6, %8, off offset:96 sc0 sc1\n\t"
          "global_load_dwordx4 %7, %8, off offset:112 sc0 sc1\n\t"
          "s_waitcnt vmcnt(0)"
          : "=&v"(r0), "=&v"(r1), "=&v"(r2), "=&v"(r3),
            "=&v"(r4), "=&v"(r5), "=&v"(r6), "=&v"(r7)
          : "v"(base) : "memory");
        ok = true;
#pragma unroll
        for (int i = 0; i < 4; ++i) {
          ok = ok && ((r0[i] & 0xFFFFu) == want) && ((r1[i] & 0xFFFFu) == want)
                  && ((r2[i] & 0xFFFFu) == want) && ((r3[i] & 0xFFFFu) == want)
                  && ((r4[i] & 0xFFFFu) == want) && ((r5[i] & 0xFFFFu) == want)
                  && ((r6[i] & 0xFFFFu) == want) && ((r7[i] & 0xFFFFu) == want);
        }
      } while (!ok);
      u16x8 d0, d1, d2, d3;
#pragma unroll
      for (int i = 0; i < 4; ++i) {
        d0[i] = (u16)(r0[i] >> 16); d0[4 + i] = (u16)(r1[i] >> 16);
        d1[i] = (u16)(r2[i] >> 16); d1[4 + i] = (u16)(r3[i] >> 16);
        d2[i] = (u16)(r4[i] >> 16); d2[4 + i] = (u16)(r5[i] >> 16);
        d3[i] = (u16)(r6[i] >> 16); d3[4 + i] = (u16)(r7[i] >> 16);
      }
      *(u16x8*)&As[prow][pcb]      = d0;
      *(u16x8*)&As[prow][pcb + 8]  = d1;
      *(u16x8*)&As[prow][pcb + 16] = d2;
      *(u16x8*)&As[prow][pcb + 24] = d3;
    }
    __syncthreads();                  // barrier 1: stage -> MFMA

    // ---- MFMA: M=16, N=32 (2 frags), K=640 ----
    f32x4 acc0 = {}, acc1 = {};
#pragma unroll
    for (int kt = 0; kt < 20; ++kt) {
      bf16x8 a = *(const bf16x8*)&As[cl][kt * 32 + ko];
      acc0 = __builtin_amdgcn_mfma_f32_16x16x32_bf16(a, wf0[kt], acc0, 0, 0, 0);
      acc1 = __builtin_amdgcn_mfma_f32_16x16x32_bf16(a, wf1[kt], acc1, 0, 0, 0);
    }

    // ---- gate exchange ----
    {
      const int rr = (lane >> 4) * 4;
#pragma unroll
      for (int r = 0; r < 4; ++r) {
        Gs[gw][rr + r][cl]      = acc0[r];
        Gs[gw][rr + r][16 + cl] = acc1[r];
      }
    }
    __syncthreads();                  // barrier 2: exchange -> update

    // ---- cell update + tagged h publication ----
    {
      const float2 gi = *(const float2*)&Gs[0][er][ec];
      const float2 gf = *(const float2*)&Gs[1][er][ec];
      const float2 gg = *(const float2*)&Gs[2][er][ec];
      const float2 go = *(const float2*)&Gs[3][er][ec];
      c0 = fast_sig(gf.x + bf0) * c0 + fast_sig(gi.x + bi0) * fast_tanh(gg.x + bg0);
      c1 = fast_sig(gf.y + bf1) * c1 + fast_sig(gi.y + bi1) * fast_tanh(gg.y + bg1);
      const float h0v = fast_sig(go.x + bo0) * fast_tanh(c0);
      const float h1v = fast_sig(go.y + bo1) * fast_tanh(c1);
      const uint32_t tag = (uint32_t)(s + 1);
      const uint32_t lo  = ((uint32_t)f2bf(h0v) << 16) | tag;
      const uint32_t hi  = ((uint32_t)f2bf(h1v) << 16) | tag;
      __hip_atomic_store(
          (uint64_t*)(xch32 + (((size_t)((s + 1) & 1) * NG_ + g) << 13) + (er << 9) + jb),
          ((uint64_t)hi << 32) | lo, __ATOMIC_RELAXED, __HIP_MEMORY_SCOPE_AGENT);
      float2 hv; hv.x = h0v; hv.y = h1v;
      *(float2*)(Yd + ((size_t)(br0 + er) * T_ + (s + 1)) * H_ + jb) = hv;
    }
    // no loop-end barrier: poll success next step transitively orders peers
  }
}

// ---------------------------------------------------------------------------
// Phase 2 (fused, v3): all 4 Euler steps; 64 rows x 512 cols per WG.
// 8 waves 1x8: each wave M=64 (4 m-frags), N=64 (4 n-frags). Y fp32 in regs;
// A-tile bf16 in LDS; B read DIRECT from global (L2-resident) with an
// explicit 2-slot register double-buffer (prefetch distance ~2 cc-iters
// = 8 loads in flight, covering ~200cyc L2 latency).
// ---------------------------------------------------------------------------
__launch_bounds__(512)
__global__ void ode_fused3(const float* __restrict__ tptr,
                           const u16* __restrict__ w1y,
                           const u16* __restrict__ w2v,
                           const float* __restrict__ b1,
                           const float* __restrict__ b2,
                           const float* __restrict__ w1s,
                           float* __restrict__ Yd) {
  __shared__ u16 At[64][520];

  const int tid  = threadIdx.x;
  const int lane = tid & 63;
  const int wv   = tid >> 6;          // 0..7
  const int n0w  = wv * 64;
  const size_t m0 = (size_t)blockIdx.x * 64;
  const int cl = lane & 15;
  const int rq = (lane >> 4) * 4;
  const int ko = (lane >> 4) * 8;

  float b1v[4], b2v[4], w1sv[4];
#pragma unroll
  for (int nf = 0; nf < 4; ++nf) {
    const int cg = n0w + nf * 16 + cl;
    b1v[nf] = b1[cg]; b2v[nf] = b2[cg]; w1sv[nf] = w1s[cg];
  }
  float tv[4][4];
#pragma unroll
  for (int mf = 0; mf < 4; ++mf)
#pragma unroll
    for (int r = 0; r < 4; ++r)
      tv[mf][r] = 0.25f * tptr[m0 + mf * 16 + rq + r];

  // load Y (fp32) into registers (C-frag layout, wave's 64-col band)
  f32x4 Y[4][4];
#pragma unroll
  for (int mf = 0; mf < 4; ++mf)
#pragma unroll
    for (int nf = 0; nf < 4; ++nf)
#pragma unroll
      for (int r = 0; r < 4; ++r)
        Y[mf][nf][r] = Yd[(m0 + mf * 16 + rq + r) * 512 + n0w + nf * 16 + cl];

#define WRITE_AT(EXPR)                                                        \
  do {                                                                        \
    _Pragma("unroll") for (int mf = 0; mf < 4; ++mf)                          \
    _Pragma("unroll") for (int nf = 0; nf < 4; ++nf)                          \
    _Pragma("unroll") for (int r = 0; r < 4; ++r)                             \
      At[mf * 16 + rq + r][n0w + nf * 16 + cl] = f2bf(EXPR);                  \
  } while (0)

#define GEMM_PIPE(WPTR, ACC)                                                  \
  do {                                                                        \
    const u16* wbase = (WPTR) + (size_t)(n0w + cl) * 512 + ko;                \
    bf16x8 bv[2][4];                                                          \
    _Pragma("unroll") for (int nf = 0; nf < 4; ++nf) {                        \
      bv[0][nf] = *(const bf16x8*)(wbase + nf * 16 * 512);                    \
      bv[1][nf] = *(const bf16x8*)(wbase + nf * 16 * 512 + 32);               \
    }                                                                         \
    _Pragma("unroll") for (int cc = 0; cc < 16; ++cc) {                       \
      bf16x8 af[4];                                                           \
      _Pragma("unroll") for (int mf = 0; mf < 4; ++mf)                        \
        af[mf] = *(const bf16x8*)&At[mf * 16 + cl][cc * 32 + ko];             \
      _Pragma("unroll") for (int mf = 0; mf < 4; ++mf)                        \
      _Pragma("unroll") for (int nf = 0; nf < 4; ++nf)                        \
        ACC[mf][nf] = __builtin_amdgcn_mfma_f32_16x16x32_bf16(                \
            af[mf], bv[cc & 1][nf], ACC[mf][nf], 0, 0, 0);                    \
      if (cc < 14) {                                                          \
        _Pragma("unroll") for (int nf = 0; nf < 4; ++nf)                      \
          bv[cc & 1][nf] =                                                    \
              *(const bf16x8*)(wbase + nf * 16 * 512 + (cc + 2) * 32);        \
      }                                                                       \
    }                                                                         \
  } while (0)

  WRITE_AT(Y[mf][nf][r]);
  __syncthreads();

#pragma unroll 1
  for (int k = 0; k < 4; ++k) {
    const float sk = 0.25f * k;
    // ---- GEMM1: G1 = tanh(A @ w1y^T + b1 + s*w1s) ----
    f32x4 acc[4][4] = {};
    GEMM_PIPE(w1y, acc);
    __syncthreads();                  // At reads done
    WRITE_AT(fast_tanh(acc[mf][nf][r] + b1v[nf] + sk * w1sv[nf]));
    __syncthreads();
    // ---- GEMM2: Y += dt*t*(G1 @ w2^T + b2) ----
    f32x4 acc2[4][4] = {};
    GEMM_PIPE(w2v, acc2);
    __syncthreads();                  // At reads done
#pragma unroll
    for (int mf = 0; mf < 4; ++mf)
#pragma unroll
      for (int nf = 0; nf < 4; ++nf)
#pragma unroll
        for (int r = 0; r < 4; ++r)
          Y[mf][nf][r] += tv[mf][r] * (acc2[mf][nf][r] + b2v[nf]);
    if (k < 3) {
      WRITE_AT(Y[mf][nf][r]);
      __syncthreads();
    }
  }
#undef GEMM_PIPE
#undef WRITE_AT

  // write back Y (fp32)
#pragma unroll
  for (int mf = 0; mf < 4; ++mf)
#pragma unroll
    for (int nf = 0; nf < 4; ++nf)
#pragma unroll
      for (int r = 0; r < 4; ++r)
        Yd[(m0 + mf * 16 + rq + r) * 512 + n0w + nf * 16 + cl] = Y[mf][nf][r];
}

// ---------------------------------------------------------------------------
extern "C" void kernel_launch(void* const* d_in, const int* in_sizes, int n_in,
                              void* d_out, int out_size, void* d_ws, size_t ws_size,
                              hipStream_t stream) {
  const float* x    = (const float*)d_in[0];
  const float* t    = (const float*)d_in[1];
  const float* W_ih = (const float*)d_in[2];
  const float* W_hh = (const float*)d_in[3];
  const float* b_ih = (const float*)d_in[4];
  const float* b_hh = (const float*)d_in[5];
  const float* w1   = (const float*)d_in[6];
  const float* b1   = (const float*)d_in[7];
  const float* w2   = (const float*)d_in[8];
  const float* b2   = (const float*)d_in[9];
  float* Yd = (float*)d_out;   // (B,T,H) fp32; h history and ODE state

  char* ws = (char*)d_ws;
  size_t off = 0;
  auto alloc = [&](size_t bytes) {
    void* p = ws + off;
    off += (bytes + 255) & ~(size_t)255;
    return p;
  };
  u16*      Whh_bf = (u16*)alloc((size_t)G4_ * H_ * 2);          //   2 MB
  u16*      Wih_bf = (u16*)alloc((size_t)G4_ * D_ * 2);          // 512 KB
  u16*      w1y_bf = (u16*)alloc((size_t)H_ * H_ * 2);           // 512 KB
  u16*      w2_bf  = (u16*)alloc((size_t)H_ * H_ * 2);           // 512 KB
  float*    w1s    = (float*)alloc(H_ * 4);
  float*    bsum   = (float*)alloc(G4_ * 4);
  uint32_t* xch32  = (uint32_t*)alloc((size_t)2 * B_ * H_ * 4);  // 1 MB

  prep_kernel<<<4096, 256, 0, stream>>>(W_hh, W_ih, w1, w2, b_ih, b_hh,
                                        Whh_bf, Wih_bf, w1y_bf, w2_bf, w1s, bsum, xch32, Yd);

  // Phase 1: persistent LSTM (256 WGs x 256 thr = 1 WG/CU, all resident)
  lstm_persist3<<<dim3(NG_ * NC_), 256, 0, stream>>>(x, Whh_bf, Wih_bf, bsum, Yd, xch32);

  // Phase 2: fused 4-step Euler ODE over all B*T rows
  ode_fused3<<<dim3(BT_ / 64), 512, 0, stream>>>(t, w1y_bf, w2_bf, b1, b2, w1s, Yd);
}

// Round 7
// 6656.039 us; speedup vs baseline: 1.2679x; 1.2679x over previous
//
#include <hip/hip_runtime.h>
#include <stdint.h>

// Problem dims (fixed)
#define B_  256
#define T_  1024
#define D_  128
#define H_  512
#define G4_ 2048            // 4*H
#define BT_ (B_ * T_)

// Persistent-LSTM partitioning: 16 batch groups x 16 col groups = 256 WGs
#define NG_ 16              // batch groups (16 rows each)
#define NC_ 16              // col groups (32 h-cols each)

typedef unsigned short u16;
typedef __attribute__((ext_vector_type(8))) short    bf16x8;  // 8 bf16 in 4 VGPRs
typedef __attribute__((ext_vector_type(8))) u16      u16x8;
typedef __attribute__((ext_vector_type(4))) float    f32x4;
typedef __attribute__((ext_vector_type(4))) uint32_t u32x4;

static __device__ __forceinline__ u16 f2bf(float f) {
  uint32_t u = __builtin_bit_cast(uint32_t, f);
  u += 0x7FFFu + ((u >> 16) & 1u);   // RNE
  return (u16)(u >> 16);
}

static __device__ __forceinline__ u16x8 pack8(float4 a, float4 b) {
  u16x8 p;
  p[0] = f2bf(a.x); p[1] = f2bf(a.y); p[2] = f2bf(a.z); p[3] = f2bf(a.w);
  p[4] = f2bf(b.x); p[5] = f2bf(b.y); p[6] = f2bf(b.z); p[7] = f2bf(b.w);
  return p;
}

static __device__ __forceinline__ float fast_sig(float x) {
  return 1.f / (1.f + __expf(-x));
}
static __device__ __forceinline__ float fast_tanh(float x) {
  return 1.f - 2.f / (__expf(2.f * x) + 1.f);
}

// ---------------------------------------------------------------------------
// prep: bf16 weight copies, bias sum, zero exchange buffer and out[:,0,:]
// ---------------------------------------------------------------------------
__global__ void prep_kernel(const float* __restrict__ Whh, const float* __restrict__ Wih,
                            const float* __restrict__ w1,  const float* __restrict__ w2,
                            const float* __restrict__ b_ih, const float* __restrict__ b_hh,
                            u16* __restrict__ Whh_bf, u16* __restrict__ Wih_bf,
                            u16* __restrict__ w1y_bf, u16* __restrict__ w2_bf,
                            float* __restrict__ w1s, float* __restrict__ bsum,
                            uint32_t* __restrict__ xch32, float* __restrict__ Yd) {
  const int idx = blockIdx.x * blockDim.x + threadIdx.x;
  if (idx < G4_ * H_) Whh_bf[idx] = f2bf(Whh[idx]);          // 1,048,576
  if (idx < G4_ * D_) Wih_bf[idx] = f2bf(Wih[idx]);          // 262,144
  if (idx < H_ * H_) {                                       // 262,144
    const int n = idx >> 9, k = idx & 511;
    w1y_bf[idx] = f2bf(w1[n * 513 + 1 + k]);                 // w1[:,1:]
    w2_bf[idx]  = f2bf(w2[idx]);
  }
  if (idx < H_)  w1s[idx]  = w1[idx * 513];                  // w1[:,0]
  if (idx < G4_) bsum[idx] = b_ih[idx] + b_hh[idx];
  if (idx < 2 * B_ * H_) xch32[idx] = 0;                     // 262,144 (tag 0)
  if (idx < B_ * H_) {                                       // 131,072
    const int b = idx >> 9, h = idx & 511;
    Yd[(size_t)b * T_ * H_ + h] = 0.f;                       // out[b,0,:] = h_0 = 0
  }
}

// x fp32 -> bf16 pre-conversion (33.5M elems; 16 per thread)
__global__ void xconv_kernel(const float* __restrict__ x, u16* __restrict__ xbf) {
  const size_t i = ((size_t)blockIdx.x * blockDim.x + threadIdx.x) * 16;
  const float4* s4 = (const float4*)(x + i);
  float4 a = s4[0], b = s4[1], c = s4[2], d = s4[3];
  *(u16x8*)(xbf + i)     = pack8(a, b);
  *(u16x8*)(xbf + i + 8) = pack8(c, d);
}

// ---------------------------------------------------------------------------
// Phase 1: persistent LSTM v5. Grid = 256 WGs x 256 thr (4 waves).
// WG (g,c): rows [g*16,+16), h-cols [c*32,+32). Wave gw = one gate (160 VGPR
// of weights per lane, pinned by an asm memory fence after the load loop).
//
// Exchange: SELF-VALIDATING tagged words ((bf16(h)<<16)|step per u32, u64
// relaxed agent-scope stores -> MALL). Consumers poll their own 128 B with
// 8x coalesced dwordx4 sc0 sc1 — detection and payload arrive together.
// Parity double-buffer; poll success at step s transitively proves peers
// finished reading parity (s&1) (R3 argument). Tags 1..1023; prep re-zeros.
// v5 delta: x is pre-converted bf16 (xbf) and register-prefetched one step
// ahead, removing ~900cyc of cold-HBM latency from the per-step chain.
// ---------------------------------------------------------------------------
__launch_bounds__(256, 1)
__global__ void lstm_persist4(const u16* __restrict__ xbf,
                              const u16* __restrict__ Whh_bf,
                              const u16* __restrict__ Wih_bf,
                              const float* __restrict__ bsum,
                              float* __restrict__ Yd,
                              uint32_t* __restrict__ xch32) {
  __shared__ u16   As[16][648];       // 16 x 640 bf16 A-tile (+pad)
  __shared__ float Gs[4][16][34];     // gate exchange

  const int tid  = threadIdx.x;
  const int lane = tid & 63;
  const int gw   = tid >> 6;          // gate 0..3
  const int w    = blockIdx.x;
  const int g    = (w & 7) * 2 + (w >> 7);   // batch group (XCD-affine)
  const int c    = (w >> 3) & 15;            // col group
  const int br0  = g * 16;
  const int hc0  = c * 32;

  const int cl = lane & 15;
  const int ko = (lane >> 4) * 8;

  // ---- persistent weight fragments: gate gw, cols hc0..hc0+32 ----
  bf16x8 wf0[20], wf1[20];
  {
    const int j0 = gw * H_ + hc0 + cl;
#pragma unroll
    for (int kt = 0; kt < 16; ++kt) {
      wf0[kt] = *(const bf16x8*)(Whh_bf + (size_t)j0 * H_ + kt * 32 + ko);
      wf1[kt] = *(const bf16x8*)(Whh_bf + (size_t)(j0 + 16) * H_ + kt * 32 + ko);
    }
#pragma unroll
    for (int kt = 0; kt < 4; ++kt) {
      wf0[16 + kt] = *(const bf16x8*)(Wih_bf + (size_t)j0 * D_ + kt * 32 + ko);
      wf1[16 + kt] = *(const bf16x8*)(Wih_bf + (size_t)(j0 + 16) * D_ + kt * 32 + ko);
    }
  }
  // pin the fragments: loads cannot legally sink past this memory fence
  asm volatile("" ::: "memory");

  // ---- per-thread cell state: row er, cols (jb, jb+1) ----
  const int er = tid >> 4;            // 0..15
  const int ec = (tid & 15) * 2;      // 0..30
  const int jb = hc0 + ec;
  float c0 = 0.f, c1 = 0.f;
  const float bi0 = bsum[jb],            bi1 = bsum[jb + 1];
  const float bf0 = bsum[H_ + jb],       bf1 = bsum[H_ + jb + 1];
  const float bg0 = bsum[2 * H_ + jb],   bg1 = bsum[2 * H_ + jb + 1];
  const float bo0 = bsum[3 * H_ + jb],   bo1 = bsum[3 * H_ + jb + 1];

  const int xr   = tid & 15,  xk   = tid >> 4;   // x-stage map
  const int prow = tid >> 4;                     // poll row 0..15
  const int pcb  = (tid & 15) * 32;              // poll col base (u32 words)

  // x register prefetch (one step ahead)
  const u16* xrow = xbf + (size_t)(br0 + xr) * T_ * D_ + xk * 8;
  u16x8 xa = *(const u16x8*)(xrow);   // step 0

  for (int s = 0; s < T_ - 1; ++s) {
    // ---- stage x-part (cols 512..639) from prefetch regs; issue next ----
    *(u16x8*)&As[xr][512 + xk * 8] = xa;
    xa = *(const u16x8*)(xrow + (size_t)(s + 1) * D_);   // covered by poll+MFMA

    // ---- stage h-part (cols 0..511): coalesced tagged poll ----
    if (s == 0) {
      u16x8 z = {};
#pragma unroll
      for (int i = 0; i < 4; ++i) *(u16x8*)&As[prow][pcb + i * 8] = z;
    } else {
      const char* base = (const char*)(xch32 + (((size_t)(s & 1) * NG_ + g) << 13)) + tid * 128;
      const uint32_t want = (uint32_t)s;
      u32x4 r0, r1, r2, r3, r4, r5, r6, r7;
      bool ok;
      do {
        asm volatile(
          "global_load_dwordx4 %0, %8, off sc0 sc1\n\t"
          "global_load_dwordx4 %1, %8, off offset:16 sc0 sc1\n\t"
          "global_load_dwordx4 %2, %8, off offset:32 sc0 sc1\n\t"
          "global_load_dwordx4 %3, %8, off offset:48 sc0 sc1\n\t"
          "global_load_dwordx4 %4, %8, off offset:64 sc0 sc1\n\t"
          "global_load_dwordx4 %5, %8, off offset:80 sc0 sc1\n\t"
          "global_load_dwordx4 %6, %8, off offset:96 sc0 sc1\n\t"
          "global_load_dwordx4 %7, %8, off offset:112 sc0 sc1\n\t"
          "s_waitcnt vmcnt(0)"
          : "=&v"(r0), "=&v"(r1), "=&v"(r2), "=&v"(r3),
            "=&v"(r4), "=&v"(r5), "=&v"(r6), "=&v"(r7)
          : "v"(base) : "memory");
        ok = true;
#pragma unroll
        for (int i = 0; i < 4; ++i) {
          ok = ok && ((r0[i] & 0xFFFFu) == want) && ((r1[i] & 0xFFFFu) == want)
                  && ((r2[i] & 0xFFFFu) == want) && ((r3[i] & 0xFFFFu) == want)
                  && ((r4[i] & 0xFFFFu) == want) && ((r5[i] & 0xFFFFu) == want)
                  && ((r6[i] & 0xFFFFu) == want) && ((r7[i] & 0xFFFFu) == want);
        }
      } while (!ok);
      u16x8 d0, d1, d2, d3;
#pragma unroll
      for (int i = 0; i < 4; ++i) {
        d0[i] = (u16)(r0[i] >> 16); d0[4 + i] = (u16)(r1[i] >> 16);
        d1[i] = (u16)(r2[i] >> 16); d1[4 + i] = (u16)(r3[i] >> 16);
        d2[i] = (u16)(r4[i] >> 16); d2[4 + i] = (u16)(r5[i] >> 16);
        d3[i] = (u16)(r6[i] >> 16); d3[4 + i] = (u16)(r7[i] >> 16);
      }
      *(u16x8*)&As[prow][pcb]      = d0;
      *(u16x8*)&As[prow][pcb + 8]  = d1;
      *(u16x8*)&As[prow][pcb + 16] = d2;
      *(u16x8*)&As[prow][pcb + 24] = d3;
    }
    __syncthreads();                  // barrier 1: stage -> MFMA

    // ---- MFMA: M=16, N=32 (2 frags), K=640 ----
    f32x4 acc0 = {}, acc1 = {};
#pragma unroll
    for (int kt = 0; kt < 20; ++kt) {
      bf16x8 a = *(const bf16x8*)&As[cl][kt * 32 + ko];
      acc0 = __builtin_amdgcn_mfma_f32_16x16x32_bf16(a, wf0[kt], acc0, 0, 0, 0);
      acc1 = __builtin_amdgcn_mfma_f32_16x16x32_bf16(a, wf1[kt], acc1, 0, 0, 0);
    }

    // ---- gate exchange ----
    {
      const int rr = (lane >> 4) * 4;
#pragma unroll
      for (int r = 0; r < 4; ++r) {
        Gs[gw][rr + r][cl]      = acc0[r];
        Gs[gw][rr + r][16 + cl] = acc1[r];
      }
    }
    __syncthreads();                  // barrier 2: exchange -> update

    // ---- cell update + tagged h publication ----
    {
      const float2 gi = *(const float2*)&Gs[0][er][ec];
      const float2 gf = *(const float2*)&Gs[1][er][ec];
      const float2 gg = *(const float2*)&Gs[2][er][ec];
      const float2 go = *(const float2*)&Gs[3][er][ec];
      c0 = fast_sig(gf.x + bf0) * c0 + fast_sig(gi.x + bi0) * fast_tanh(gg.x + bg0);
      c1 = fast_sig(gf.y + bf1) * c1 + fast_sig(gi.y + bi1) * fast_tanh(gg.y + bg1);
      const float h0v = fast_sig(go.x + bo0) * fast_tanh(c0);
      const float h1v = fast_sig(go.y + bo1) * fast_tanh(c1);
      const uint32_t tag = (uint32_t)(s + 1);
      const uint32_t lo  = ((uint32_t)f2bf(h0v) << 16) | tag;
      const uint32_t hi  = ((uint32_t)f2bf(h1v) << 16) | tag;
      __hip_atomic_store(
          (uint64_t*)(xch32 + (((size_t)((s + 1) & 1) * NG_ + g) << 13) + (er << 9) + jb),
          ((uint64_t)hi << 32) | lo, __ATOMIC_RELAXED, __HIP_MEMORY_SCOPE_AGENT);
      float2 hv; hv.x = h0v; hv.y = h1v;
      *(float2*)(Yd + ((size_t)(br0 + er) * T_ + (s + 1)) * H_ + jb) = hv;
    }
    // no loop-end barrier: poll success next step transitively orders peers
  }
}

// ---------------------------------------------------------------------------
// Phase 2 (fused, v2 — proven R5): all 4 Euler steps; 64 rows x 512 cols/WG.
// 8 waves, 1x8 layout: each wave M=64 (4 m-frags), N=64 (4 n-frags).
// Y fp32 in regs; A-tile (bf16 Y / G1) in LDS; B (weights) loaded DIRECTLY
// from global (512 KB, L2-resident) inside the cc-loop — no reg pipeline
// (R6's bv[2][4] pipeline spilled to scratch: 14.9 GB HBM, 2x slower).
// ---------------------------------------------------------------------------
__launch_bounds__(512)
__global__ void ode_fused2(const float* __restrict__ tptr,
                           const u16* __restrict__ w1y,
                           const u16* __restrict__ w2v,
                           const float* __restrict__ b1,
                           const float* __restrict__ b2,
                           const float* __restrict__ w1s,
                           float* __restrict__ Yd) {
  __shared__ u16 At[64][520];

  const int tid  = threadIdx.x;
  const int lane = tid & 63;
  const int wv   = tid >> 6;          // 0..7
  const int n0w  = wv * 64;
  const size_t m0 = (size_t)blockIdx.x * 64;
  const int cl = lane & 15;
  const int rq = (lane >> 4) * 4;
  const int ko = (lane >> 4) * 8;

  float b1v[4], b2v[4], w1sv[4];
#pragma unroll
  for (int nf = 0; nf < 4; ++nf) {
    const int cg = n0w + nf * 16 + cl;
    b1v[nf] = b1[cg]; b2v[nf] = b2[cg]; w1sv[nf] = w1s[cg];
  }
  float tv[4][4];
#pragma unroll
  for (int mf = 0; mf < 4; ++mf)
#pragma unroll
    for (int r = 0; r < 4; ++r)
      tv[mf][r] = 0.25f * tptr[m0 + mf * 16 + rq + r];

  // load Y (fp32) into registers (C-frag layout, wave's 64-col band)
  f32x4 Y[4][4];
#pragma unroll
  for (int mf = 0; mf < 4; ++mf)
#pragma unroll
    for (int nf = 0; nf < 4; ++nf)
#pragma unroll
      for (int r = 0; r < 4; ++r)
        Y[mf][nf][r] = Yd[(m0 + mf * 16 + rq + r) * 512 + n0w + nf * 16 + cl];

#define WRITE_AT(EXPR)                                                        \
  do {                                                                        \
    _Pragma("unroll") for (int mf = 0; mf < 4; ++mf)                          \
    _Pragma("unroll") for (int nf = 0; nf < 4; ++nf)                          \
    _Pragma("unroll") for (int r = 0; r < 4; ++r)                             \
      At[mf * 16 + rq + r][n0w + nf * 16 + cl] = f2bf(EXPR);                  \
  } while (0)

#define GEMM_DIRECT(WPTR, ACC)                                                \
  do {                                                                        \
    _Pragma("unroll 2") for (int cc = 0; cc < 16; ++cc) {                     \
      bf16x8 bfv[4], af[4];                                                   \
      _Pragma("unroll") for (int nf = 0; nf < 4; ++nf)                        \
        bfv[nf] = *(const bf16x8*)((WPTR) + (size_t)(n0w + nf * 16 + cl) * 512\
                                   + cc * 32 + ko);                           \
      _Pragma("unroll") for (int mf = 0; mf < 4; ++mf)                        \
        af[mf] = *(const bf16x8*)&At[mf * 16 + cl][cc * 32 + ko];             \
      _Pragma("unroll") for (int mf = 0; mf < 4; ++mf)                        \
      _Pragma("unroll") for (int nf = 0; nf < 4; ++nf)                        \
        ACC[mf][nf] = __builtin_amdgcn_mfma_f32_16x16x32_bf16(                \
            af[mf], bfv[nf], ACC[mf][nf], 0, 0, 0);                           \
    }                                                                         \
  } while (0)

  WRITE_AT(Y[mf][nf][r]);
  __syncthreads();

#pragma unroll 1
  for (int k = 0; k < 4; ++k) {
    const float sk = 0.25f * k;
    // ---- GEMM1: G1 = tanh(A @ w1y^T + b1 + s*w1s) ----
    f32x4 acc[4][4] = {};
    GEMM_DIRECT(w1y, acc);
    __syncthreads();                  // At reads done
    WRITE_AT(fast_tanh(acc[mf][nf][r] + b1v[nf] + sk * w1sv[nf]));
    __syncthreads();
    // ---- GEMM2: Y += dt*t*(G1 @ w2^T + b2) ----
    f32x4 acc2[4][4] = {};
    GEMM_DIRECT(w2v, acc2);
    __syncthreads();                  // At reads done
#pragma unroll
    for (int mf = 0; mf < 4; ++mf)
#pragma unroll
      for (int nf = 0; nf < 4; ++nf)
#pragma unroll
        for (int r = 0; r < 4; ++r)
          Y[mf][nf][r] += tv[mf][r] * (acc2[mf][nf][r] + b2v[nf]);
    if (k < 3) {
      WRITE_AT(Y[mf][nf][r]);
      __syncthreads();
    }
  }
#undef GEMM_DIRECT
#undef WRITE_AT

  // write back Y (fp32)
#pragma unroll
  for (int mf = 0; mf < 4; ++mf)
#pragma unroll
    for (int nf = 0; nf < 4; ++nf)
#pragma unroll
      for (int r = 0; r < 4; ++r)
        Yd[(m0 + mf * 16 + rq + r) * 512 + n0w + nf * 16 + cl] = Y[mf][nf][r];
}

// ---------------------------------------------------------------------------
extern "C" void kernel_launch(void* const* d_in, const int* in_sizes, int n_in,
                              void* d_out, int out_size, void* d_ws, size_t ws_size,
                              hipStream_t stream) {
  const float* x    = (const float*)d_in[0];
  const float* t    = (const float*)d_in[1];
  const float* W_ih = (const float*)d_in[2];
  const float* W_hh = (const float*)d_in[3];
  const float* b_ih = (const float*)d_in[4];
  const float* b_hh = (const float*)d_in[5];
  const float* w1   = (const float*)d_in[6];
  const float* b1   = (const float*)d_in[7];
  const float* w2   = (const float*)d_in[8];
  const float* b2   = (const float*)d_in[9];
  float* Yd = (float*)d_out;   // (B,T,H) fp32; h history and ODE state

  char* ws = (char*)d_ws;
  size_t off = 0;
  auto alloc = [&](size_t bytes) {
    void* p = ws + off;
    off += (bytes + 255) & ~(size_t)255;
    return p;
  };
  u16*      Whh_bf = (u16*)alloc((size_t)G4_ * H_ * 2);          //   2 MB
  u16*      Wih_bf = (u16*)alloc((size_t)G4_ * D_ * 2);          // 512 KB
  u16*      w1y_bf = (u16*)alloc((size_t)H_ * H_ * 2);           // 512 KB
  u16*      w2_bf  = (u16*)alloc((size_t)H_ * H_ * 2);           // 512 KB
  float*    w1s    = (float*)alloc(H_ * 4);
  float*    bsum   = (float*)alloc(G4_ * 4);
  uint32_t* xch32  = (uint32_t*)alloc((size_t)2 * B_ * H_ * 4);  // 1 MB
  u16*      xbf    = (u16*)alloc((size_t)BT_ * D_ * 2);          // 64 MB

  prep_kernel<<<4096, 256, 0, stream>>>(W_hh, W_ih, w1, w2, b_ih, b_hh,
                                        Whh_bf, Wih_bf, w1y_bf, w2_bf, w1s, bsum, xch32, Yd);
  xconv_kernel<<<8192, 256, 0, stream>>>(x, xbf);

  // Phase 1: persistent LSTM (256 WGs x 256 thr = 1 WG/CU, all resident)
  lstm_persist4<<<dim3(NG_ * NC_), 256, 0, stream>>>(xbf, Whh_bf, Wih_bf, bsum, Yd, xch32);

  // Phase 2: fused 4-step Euler ODE over all B*T rows
  ode_fused2<<<dim3(BT_ / 64), 512, 0, stream>>>(t, w1y_bf, w2_bf, b1, b2, w1s, Yd);
}